// Round 1
// 109.294 us; speedup vs baseline: 1.0098x; 1.0098x over previous
//
#include <hip/hip_runtime.h>

typedef unsigned int u32;

// Only the low 16 bits of every hash product matter (final % 65536, XOR is
// bitwise, mul distributes over mod 2^16) -> masked primes + __umul24.
__device__ constexpr u32 BASEP[16] = {
    2654435761u, 2246822519u, 3266489917u, 2028178513u,
    1220703125u, 1610612741u,  805306457u,  402653189u,
    3674653429u, 2860486313u, 1073676287u, 2971215073u,
    1500450271u, 3267000013u, 2654435789u, 4049292737u};
__device__ constexpr u32 EXTP[16] = {   // EXT32[16..31]
    2246822531u, 3266489927u, 2028178519u, 1220703133u,
    1610612759u,  805306463u,  402653201u, 3674653441u,
    2860486319u, 1073676311u, 2971215091u, 1500450277u,
    3267000023u, 2654435801u, 4049292751u, 2246822537u};

#define TDIM 4096
#define PPB  64          // positions per 256-thread block (4 per thread)
#define HALO 128
#define NTOK (HALO + PPB)

// ---- cross-lane butterfly on the VALU pipe (DPP), 16-lane groups ----------
// The DS pipe (ds_swizzle from __shfl_xor) is per-CU shared by 4 SIMDs and was
// the bottleneck; DPP runs on the per-SIMD VALU. Tree order d=1,2,4,8 kept
// identical to the verified shfl version -> bit-identical results.
// row_shr:N => lane i reads lane i-N (LLVM AtomicOptimizer reduce pattern);
// row_shl:N => lane i reads lane i+N.
__device__ __forceinline__ int dpp_x1(int x) {        // lane ^ 1
    return __builtin_amdgcn_update_dpp(0, x, 0xB1, 0xF, 0xF, true);
}
__device__ __forceinline__ int dpp_x2(int x) {        // lane ^ 2
    return __builtin_amdgcn_update_dpp(0, x, 0x4E, 0xF, 0xF, true);
}
__device__ __forceinline__ int dpp_x4(int x) {        // lane ^ 4 (2-op pair)
    int y = __builtin_amdgcn_update_dpp(0, x, 0x104, 0xF, 0x5, false); // shl:4 -> banks 0,2 (i&4==0 get i+4)
    return  __builtin_amdgcn_update_dpp(y, x, 0x114, 0xF, 0xA, false); // shr:4 -> banks 1,3 (i&4   get i-4)
}
__device__ __forceinline__ int dpp_x8(int x) {        // lane ^ 8 (ror:8 == xor8 in 16)
    return __builtin_amdgcn_update_dpp(0, x, 0x128, 0xF, 0xF, true);
}
__device__ __forceinline__ u32 bxor16(u32 x) {        // XOR across 16-lane group
    x ^= (u32)dpp_x1((int)x);
    x ^= (u32)dpp_x2((int)x);
    x ^= (u32)dpp_x4((int)x);
    x ^= (u32)dpp_x8((int)x);
    return x;
}
__device__ __forceinline__ float fsum16(float x) {    // ADD across 16-lane group
    x += __int_as_float(dpp_x1(__float_as_int(x)));
    x += __int_as_float(dpp_x2(__float_as_int(x)));
    x += __int_as_float(dpp_x4(__float_as_int(x)));
    x += __int_as_float(dpp_x8(__float_as_int(x)));
    return x;
}

// Thread = (slot = tid>>4, r = tid&15); r doubles as (s = r>>2, q = r&3) for
// the gather phase. Each thread covers positions slot + 16*it, it = 0..3:
// consecutive its shift the hash window by 16, so token regs shift-register
// (v_m(it+1) = v_{m-1}(it)) -> 11 token LDS reads instead of 32.
__global__ __launch_bounds__(256) void rhp_fused(
        const int* __restrict__ tokens, const float* __restrict__ tables,
        const float* __restrict__ Wc, float* __restrict__ out)
{
    __shared__ u32   toks[NTOK];         // 192 tokens (halo zero-padded)
    __shared__ float wc_s[512];          // 8 x 64
    __shared__ u32   bp16[16], ep16[16]; // masked primes

    const int tid = threadIdx.x;
    const int g0  = blockIdx.x * PPB;        // flat position of tile start
    const int t0  = g0 & (TDIM - 1);         // 64 | 4096 -> no row straddle

    if (tid < 16) { bp16[tid] = BASEP[tid] & 0xFFFFu;
                    ep16[tid] = EXTP[tid]  & 0xFFFFu; }
    if (tid < 128) ((float4*)wc_s)[tid] = ((const float4*)Wc)[tid];
    if (tid < NTOK) {
        const int t = t0 - HALO + tid;       // in-row index; <0 -> zero pad
        toks[tid] = (t >= 0) ? (u32)tokens[g0 - HALO + tid] : 0u;
    }
    __syncthreads();

    const int r    = tid & 15;
    const int slot = tid >> 4;
    const int s    = (tid >> 2) & 3;
    const int q    = tid & 3;

    // Wc fragments are position-invariant for a thread -> hoist to registers
    float4 w[8];
#pragma unroll
    for (int j = 0; j < 8; ++j) w[j] = ((const float4*)wc_s)[j * 16 + s * 4 + q];

    const u32 pb  = bp16[r];                 // BASE[r] & 0xFFFF
    const u32 pb7 = bp16[r & 7];             // BASE[r&7] & 0xFFFF
    const u32 pe  = ep16[r];                 // EXT32[16+r] & 0xFFFF
    const u32 p7  = pb7 ^ 0xF00Du;           // ^0x8BADF00D (low 16)
    const u32 p6  = pb7 ^ 0xBABEu;           // ^0xCAFEBABE
    const u32 p5a = pb  ^ 0xBEEFu;           // ^0xDEADBEEF, i = r
    const u32 p5b = pe  ^ 0xBEEFu;           //              i = r+16

    // hash term index i = r + 16m; token idx = HALO + p - 1 - i
    const int base = HALO - 1 + slot - r;    // it=0: min 112-15=... >=0, max 142
    u32 v0 = toks[base      ], v1 = toks[base -  16];
    u32 v2 = toks[base -  32], v3 = toks[base -  48];
    u32 v4 = toks[base -  64], v5 = toks[base -  80];
    u32 v6 = toks[base -  96], v7 = toks[base - 112];

    const float* tshort = tables + (u32)s * 1048576u + (u32)q * 4u;
    const float* tlong  = tshort + 4u * 1048576u;
    float* o = out + (size_t)(g0 + slot) * 128u + (u32)s * 16u + (u32)q * 4u;

#pragma unroll
    for (int it = 0; it < 4; ++it) {
        u32 k7 = __umul24(v0, p7) ^ __umul24(v1, p7) ^ __umul24(v2, p7) ^
                 __umul24(v3, p7) ^ __umul24(v4, p7) ^ __umul24(v5, p7) ^
                 __umul24(v6, p7) ^ __umul24(v7, p7);
        u32 k6 = __umul24(v0, p6) ^ __umul24(v1, p6) ^
                 __umul24(v2, p6) ^ __umul24(v3, p6);
        u32 k5 = __umul24(v0, p5a) ^ __umul24(v1, p5b);
        u32 k4 = __umul24(v0, pb);
        const u32 k3 = (r < 8) ? k4 : 0u;    // k0..k3 reuse k4's i=r term
        const u32 k2 = (r < 4) ? k4 : 0u;
        const u32 k1 = (r < 2) ? k4 : 0u;
        const u32 k0 = (r == 0) ? k4 : 0u;

        // pack short|long<<16 per scale-pair, DPP-butterfly over 16 lanes
        u32 P0 = (k0 & 0xFFFFu) | ((k4 & 0xFFFFu) << 16);
        u32 P1 = (k1 & 0xFFFFu) | ((k5 & 0xFFFFu) << 16);
        u32 P2 = (k2 & 0xFFFFu) | ((k6 & 0xFFFFu) << 16);
        u32 P3 = (k3 & 0xFFFFu) | ((k7 & 0xFFFFu) << 16);
        P0 = bxor16(P0); P1 = bxor16(P1); P2 = bxor16(P2); P3 = bxor16(P3);

        const u32 Ps = (s == 0) ? P0 : (s == 1) ? P1 : (s == 2) ? P2 : P3;
        const u32 ks = Ps & 0xFFFFu;

        // ---- short gather: quad-coalesced 64B row (4 lanes x float4) ----
        const float4 sv = *(const float4*)(tshort + ks * 16u);
        *(float4*)o = sv;

        // ---- partial logits over this lane's 4 columns ----
        float lg[8];
#pragma unroll
        for (int j = 0; j < 8; ++j)
            lg[j] = fmaf(sv.x, w[j].x, fmaf(sv.y, w[j].y,
                     fmaf(sv.z, w[j].z, sv.w * w[j].w)));
#pragma unroll
        for (int j = 0; j < 8; ++j) lg[j] = fsum16(lg[j]);

        u32 ck = 0u;
#pragma unroll
        for (int j = 0; j < 8; ++j)
            if (lg[j] > 0.0f) ck ^= (BASEP[j] & 0xFFFFu);  // low 16 suffice

        // ---- long gather: tables[s+4][(k_{s+4} ^ ck) % 65536] ----
        const u32 kl = ((Ps >> 16) ^ ck) & 0xFFFFu;
        const float4 lv = *(const float4*)(tlong + kl * 16u);
        *(float4*)(o + 64u) = lv;

        if (it < 3) {
            v7 = v6; v6 = v5; v5 = v4; v4 = v3;   // window shifts by 16
            v3 = v2; v2 = v1; v1 = v0;
            v0 = toks[base + 16 * (it + 1)];
            o += 16 * 128;                         // position += 16
        }
    }
}

extern "C" void kernel_launch(void* const* d_in, const int* in_sizes, int n_in,
                              void* d_out, int out_size, void* d_ws, size_t ws_size,
                              hipStream_t stream) {
    const int*   tokens = (const int*)d_in[0];
    const float* tables = (const float*)d_in[1];
    const float* Wc     = (const float*)d_in[2];
    float*       out    = (float*)d_out;

    const int n_pos = in_sizes[0];             // B*T = 131072
    hipLaunchKernelGGL(rhp_fused, dim3(n_pos / PPB), dim3(256), 0, stream,
                       tokens, tables, Wc, out);
}

// Round 3
// 107.884 us; speedup vs baseline: 1.0230x; 1.0131x over previous
//
#include <hip/hip_runtime.h>

typedef unsigned int u32;
typedef float f4 __attribute__((ext_vector_type(4)));  // native vec for nt-store

// Only the low 16 bits of every hash product matter (final % 65536, XOR is
// bitwise, mul distributes over mod 2^16) -> masked primes + __umul24.
__device__ constexpr u32 BASEP[16] = {
    2654435761u, 2246822519u, 3266489917u, 2028178513u,
    1220703125u, 1610612741u,  805306457u,  402653189u,
    3674653429u, 2860486313u, 1073676287u, 2971215073u,
    1500450271u, 3267000013u, 2654435789u, 4049292737u};
__device__ constexpr u32 EXTP[16] = {   // EXT32[16..31]
    2246822531u, 3266489927u, 2028178519u, 1220703133u,
    1610612759u,  805306463u,  402653201u, 3674653441u,
    2860486319u, 1073676311u, 2971215091u, 1500450277u,
    3267000023u, 2654435801u, 4049292751u, 2246822537u};

#define TDIM 4096
#define PPB  64          // positions per 256-thread block (4 per thread)
#define HALO 128
#define NTOK (HALO + PPB)

// ---- cross-lane butterfly on the VALU pipe (DPP), 16-lane groups ----------
// Tree order d=1,2,4,8 identical to the verified shfl version -> bit-identical.
__device__ __forceinline__ int dpp_x1(int x) {        // lane ^ 1
    return __builtin_amdgcn_update_dpp(0, x, 0xB1, 0xF, 0xF, true);
}
__device__ __forceinline__ int dpp_x2(int x) {        // lane ^ 2
    return __builtin_amdgcn_update_dpp(0, x, 0x4E, 0xF, 0xF, true);
}
__device__ __forceinline__ int dpp_x4(int x) {        // lane ^ 4 (2-op pair)
    int y = __builtin_amdgcn_update_dpp(0, x, 0x104, 0xF, 0x5, false); // shl:4 -> banks 0,2
    return  __builtin_amdgcn_update_dpp(y, x, 0x114, 0xF, 0xA, false); // shr:4 -> banks 1,3
}
__device__ __forceinline__ int dpp_x8(int x) {        // lane ^ 8 (ror:8 == xor8 in 16)
    return __builtin_amdgcn_update_dpp(0, x, 0x128, 0xF, 0xF, true);
}
__device__ __forceinline__ u32 bxor16(u32 x) {        // XOR across 16-lane group
    x ^= (u32)dpp_x1((int)x);
    x ^= (u32)dpp_x2((int)x);
    x ^= (u32)dpp_x4((int)x);
    x ^= (u32)dpp_x8((int)x);
    return x;
}
__device__ __forceinline__ float fsum16(float x) {    // ADD across 16-lane group
    x += __int_as_float(dpp_x1(__float_as_int(x)));
    x += __int_as_float(dpp_x2(__float_as_int(x)));
    x += __int_as_float(dpp_x4(__float_as_int(x)));
    x += __int_as_float(dpp_x8(__float_as_int(x)));
    return x;
}

// Thread = (slot = tid>>4, r = tid&15); r doubles as (s = r>>2, q = r&3) for
// the gather phase. Each thread covers positions slot + 16*it, it = 0..3.
// Phase 1 computes ALL four packed keys from tokens (shift-register window),
// phase 2 issues all four short gathers back-to-back (4-deep MLP), phase 3
// pipelines logits->long-gather across iterations, phase 4 drains long stores.
// All out stores are nontemporal: out is write-once, and dirtying L2 with
// 67 MB of stores evicts the table rows the gathers need.
__global__ __launch_bounds__(256) void rhp_fused(
        const int* __restrict__ tokens, const float* __restrict__ tables,
        const float* __restrict__ Wc, float* __restrict__ out)
{
    __shared__ u32   toks[NTOK];         // 192 tokens (halo zero-padded)
    __shared__ float wc_s[512];          // 8 x 64
    __shared__ u32   bp16[16], ep16[16]; // masked primes

    const int tid = threadIdx.x;
    const int g0  = blockIdx.x * PPB;        // flat position of tile start
    const int t0  = g0 & (TDIM - 1);         // 64 | 4096 -> no row straddle

    if (tid < 16) { bp16[tid] = BASEP[tid] & 0xFFFFu;
                    ep16[tid] = EXTP[tid]  & 0xFFFFu; }
    if (tid < 128) ((float4*)wc_s)[tid] = ((const float4*)Wc)[tid];
    if (tid < NTOK) {
        const int t = t0 - HALO + tid;       // in-row index; <0 -> zero pad
        toks[tid] = (t >= 0) ? (u32)tokens[g0 - HALO + tid] : 0u;
    }
    __syncthreads();

    const int r    = tid & 15;
    const int slot = tid >> 4;
    const int s    = (tid >> 2) & 3;
    const int q    = tid & 3;

    // Wc fragments are position-invariant for a thread -> hoist to registers
    float4 w[8];
#pragma unroll
    for (int j = 0; j < 8; ++j) w[j] = ((const float4*)wc_s)[j * 16 + s * 4 + q];

    const u32 pb  = bp16[r];                 // BASE[r] & 0xFFFF
    const u32 pb7 = bp16[r & 7];             // BASE[r&7] & 0xFFFF
    const u32 pe  = ep16[r];                 // EXT32[16+r] & 0xFFFF
    const u32 p7  = pb7 ^ 0xF00Du;           // ^0x8BADF00D (low 16)
    const u32 p6  = pb7 ^ 0xBABEu;           // ^0xCAFEBABE
    const u32 p5a = pb  ^ 0xBEEFu;           // ^0xDEADBEEF, i = r
    const u32 p5b = pe  ^ 0xBEEFu;           //              i = r+16

    // ---- phase 1: packed keys for all four positions (token-only inputs) ---
    const int base = HALO - 1 + slot - r;    // term i = r+16m -> toks[base-16m]
    u32 v0 = toks[base      ], v1 = toks[base -  16];
    u32 v2 = toks[base -  32], v3 = toks[base -  48];
    u32 v4 = toks[base -  64], v5 = toks[base -  80];
    u32 v6 = toks[base -  96], v7 = toks[base - 112];

    u32 Pk[4];
#pragma unroll
    for (int it = 0; it < 4; ++it) {
        u32 k7 = __umul24(v0, p7) ^ __umul24(v1, p7) ^ __umul24(v2, p7) ^
                 __umul24(v3, p7) ^ __umul24(v4, p7) ^ __umul24(v5, p7) ^
                 __umul24(v6, p7) ^ __umul24(v7, p7);
        u32 k6 = __umul24(v0, p6) ^ __umul24(v1, p6) ^
                 __umul24(v2, p6) ^ __umul24(v3, p6);
        u32 k5 = __umul24(v0, p5a) ^ __umul24(v1, p5b);
        u32 k4 = __umul24(v0, pb);
        const u32 k3 = (r < 8) ? k4 : 0u;    // k0..k3 reuse k4's i=r term
        const u32 k2 = (r < 4) ? k4 : 0u;
        const u32 k1 = (r < 2) ? k4 : 0u;
        const u32 k0 = (r == 0) ? k4 : 0u;

        u32 P0 = (k0 & 0xFFFFu) | ((k4 & 0xFFFFu) << 16);
        u32 P1 = (k1 & 0xFFFFu) | ((k5 & 0xFFFFu) << 16);
        u32 P2 = (k2 & 0xFFFFu) | ((k6 & 0xFFFFu) << 16);
        u32 P3 = (k3 & 0xFFFFu) | ((k7 & 0xFFFFu) << 16);
        P0 = bxor16(P0); P1 = bxor16(P1); P2 = bxor16(P2); P3 = bxor16(P3);
        Pk[it] = (s == 0) ? P0 : (s == 1) ? P1 : (s == 2) ? P2 : P3;

        if (it < 3) {
            v7 = v6; v6 = v5; v5 = v4; v4 = v3;   // window shifts by 16
            v3 = v2; v2 = v1; v1 = v0;
            v0 = toks[base + 16 * (it + 1)];
        }
    }

    const float* tshort = tables + (u32)s * 1048576u + (u32)q * 4u;
    const float* tlong  = tshort + 4u * 1048576u;
    float* o = out + (size_t)(g0 + slot) * 128u + (u32)s * 16u + (u32)q * 4u;

    // ---- phase 2: issue all four short gathers (4-deep MLP) ----
    float4 sv[4];
#pragma unroll
    for (int it = 0; it < 4; ++it)
        sv[it] = *(const float4*)(tshort + (Pk[it] & 0xFFFFu) * 16u);

    // ---- phase 3: logits -> long gather, pipelined across iterations ----
    float4 lv[4];
#pragma unroll
    for (int it = 0; it < 4; ++it) {
        float lg[8];
#pragma unroll
        for (int j = 0; j < 8; ++j)
            lg[j] = fmaf(sv[it].x, w[j].x, fmaf(sv[it].y, w[j].y,
                     fmaf(sv[it].z, w[j].z, sv[it].w * w[j].w)));
#pragma unroll
        for (int j = 0; j < 8; ++j) lg[j] = fsum16(lg[j]);

        u32 ck = 0u;
#pragma unroll
        for (int j = 0; j < 8; ++j)
            if (lg[j] > 0.0f) ck ^= (BASEP[j] & 0xFFFFu);  // low 16 suffice

        const u32 kl = ((Pk[it] >> 16) ^ ck) & 0xFFFFu;
        lv[it] = *(const float4*)(tlong + kl * 16u);

        __builtin_nontemporal_store((f4){sv[it].x, sv[it].y, sv[it].z, sv[it].w},
                                    (f4*)(o + it * 2048));
    }

    // ---- phase 4: drain long stores (longs overlap phase-3 compute) ----
#pragma unroll
    for (int it = 0; it < 4; ++it)
        __builtin_nontemporal_store((f4){lv[it].x, lv[it].y, lv[it].z, lv[it].w},
                                    (f4*)(o + it * 2048 + 64));
}

extern "C" void kernel_launch(void* const* d_in, const int* in_sizes, int n_in,
                              void* d_out, int out_size, void* d_ws, size_t ws_size,
                              hipStream_t stream) {
    const int*   tokens = (const int*)d_in[0];
    const float* tables = (const float*)d_in[1];
    const float* Wc     = (const float*)d_in[2];
    float*       out    = (float*)d_out;

    const int n_pos = in_sizes[0];             // B*T = 131072
    hipLaunchKernelGGL(rhp_fused, dim3(n_pos / PPB), dim3(256), 0, stream,
                       tokens, tables, Wc, out);
}